// Round 7
// baseline (9936.842 us; speedup 1.0000x reference)
//
#include <hip/hip_runtime.h>
#include <hip/hip_bf16.h>
#include <stdint.h>

#define T_LEN 4096
#define D_DIM 256
#define HDIM 256
#define G4 1024          // 4*HD gate rows per direction
#define NTAGS 32
#define START_TAG 30
#define STOP_TAG 31

typedef unsigned long long u64;
typedef unsigned int u32;

__device__ __forceinline__ float sigf(float x){ return 1.0f/(1.0f+expf(-x)); }

// ---------------------------------------------------------------------------
// K1: embedding gather + input projections xg = E[seq] @ Wih^T + (bih+bhh)
// ---------------------------------------------------------------------------
__global__ __launch_bounds__(256) void k_xg(const int* __restrict__ seq,
    const float* __restrict__ E,
    const float* __restrict__ Wf, const float* __restrict__ bihf, const float* __restrict__ bhhf,
    const float* __restrict__ Wb, const float* __restrict__ bihb, const float* __restrict__ bhhb,
    float* __restrict__ xg_f, float* __restrict__ xg_b)
{
    __shared__ __align__(16) float xsh[8][D_DIM];
    __shared__ int sq[8];
    const int b = blockIdx.x, tb = b >> 3, cb = b & 7, j = threadIdx.x;
    if (j < 8) sq[j] = seq[tb*8 + j];
    __syncthreads();
    #pragma unroll
    for (int r = 0; r < 8; ++r) xsh[r][j] = E[(size_t)sq[r]*D_DIM + j];
    __syncthreads();
    const int col = cb*256 + j;      // 0..2047
    const int d   = col >> 10;       // 0 fwd, 1 bwd
    const int row = col & 1023;
    const float* W = d ? Wb : Wf;
    const float bias = d ? (bihb[row] + bhhb[row]) : (bihf[row] + bhhf[row]);
    const float4* wr = reinterpret_cast<const float4*>(W + (size_t)row*D_DIM);
    float acc[8];
    #pragma unroll
    for (int r=0;r<8;++r) acc[r] = 0.f;
    for (int kk = 0; kk < D_DIM/4; ++kk){
        float4 wv = wr[kk];
        #pragma unroll
        for (int r=0;r<8;++r){
            float4 xv = reinterpret_cast<const float4*>(xsh[r])[kk];
            acc[r] = fmaf(wv.x, xv.x, fmaf(wv.y, xv.y, fmaf(wv.z, xv.z, fmaf(wv.w, xv.w, acc[r]))));
        }
    }
    #pragma unroll
    for (int r=0;r<8;++r){
        const int t = tb*8 + r;
        const float v = acc[r] + bias;
        if (d == 0) xg_f[(size_t)t*G4 + row] = v;
        else        xg_b[(size_t)(T_LEN-1-t)*G4 + row] = v;
    }
}

// ---------------------------------------------------------------------------
// K2: bidirectional LSTM. 16 persistent blocks (2 dir x 8). Each block owns
// 32 units = 128 gate rows, weights f32 LDS-resident (128KB), XOR-swizzled
// row-major for b128 reads. r7 structure:
//  * row permutation rb = u_loc*4 + gate -> all 4 gates of a unit in ONE
//    wave: gate combine = 3 in-wave shuffles. No partial buffer/barrier.
//  * k split 2-way across adjacent lanes (half = l&1), combined by
//    __shfl_xor(1). Thread = half gate-row = 128 MACs.
//  * ONE barrier/step (cross-wave h_sh share), h_sh parity double-buffered.
//    Safety: barrier t separates step t-1 reads of buffer (t+1)&1 from step
//    t's producer writes to it; poll writes touch only buffer t&1.
//  * own-block units bypass LLC: producer writes h_sh[(t+1)&1][ug] directly;
//    only the 224 foreign units are polled.
// Exchange: r1-proven packed (tag<<32|h_bits) relaxed agent atomics, parity
// double-buffered, tight poll. Replay-safe (tag induction unchanged).
// ---------------------------------------------------------------------------
__global__ __launch_bounds__(256,1) void k_lstm(
    const float* __restrict__ Whh_f, const float* __restrict__ Whh_b,
    const float* __restrict__ xgf, const float* __restrict__ xgb,
    const float* __restrict__ h0, const float* __restrict__ c0,
    float* __restrict__ hs_f, float* __restrict__ hs_b,
    u64* __restrict__ hbuf_all)
{
    const int blk = blockIdx.x;       // 0..15
    const int d   = blk >> 3;         // direction
    const int sb  = blk & 7;          // sub-block within direction
    const int ulo = sb * 32;          // first owned unit
    const int j = threadIdx.x;        // 0..255
    const int w = j >> 6;             // wave id
    const int l = j & 63;             // lane
    const int half = l & 1;           // k-half: 0 -> k[0,128), 1 -> k[128,256)
    const int rb   = w*32 + (l >> 1); // block-local row in [0,128), = u_loc*4+g
    const int g_r  = rb & 3;          // gate (0:i 1:f 2:g 3:o)
    const int u_loc= rb >> 2;         // local unit [0,32); wave w: [8w,8w+8)
    const int row_global = g_r*256 + ulo + u_loc;
    const bool prod = ((l & 7) == 0); // i-gate even lane: producer for unit...
    const int ug = ulo + w*8 + (l >> 3);   // producer lane's global unit

    const float* __restrict__ Whh = d ? Whh_b : Whh_f;
    const float* __restrict__ xg  = d ? xgb : xgf;
    float* __restrict__ hs = d ? hs_b : hs_f;
    u64* __restrict__ hb = hbuf_all + (size_t)d*2*HDIM;   // [parity][unit]

    __shared__ __align__(16) char wbuf[128*1024];   // [rb][k] f32, swizzled
    __shared__ float h_sh[2][HDIM];                 // parity double-buffer

    // ---- stage weights: thread stages exactly its read set (row rb, half) ----
    {
        const float4* src = reinterpret_cast<const float4*>(Whh + (size_t)row_global*HDIM + half*128);
        #pragma unroll
        for (int i = 0; i < 32; ++i){
            const int byte = (rb*1024 + half*512 + i*16) ^ ((rb&7)<<4);
            *reinterpret_cast<float4*>(wbuf + byte) = src[i];
        }
    }
    h_sh[0][j] = h0[d*HDIM + j];
    float c = 0.0f;
    if (prod) c = c0[d*HDIM + ug];
    float xgc = (half == 0) ? xg[row_global] : 0.0f;
    __syncthreads();

    for (int t = 0; t < T_LEN; ++t){
        const int par = t & 1;
        if (t > 0){
            const bool own = (j >= ulo) && (j < ulo + 32);
            if (!own){
                const u32 want = (u32)t;
                u64* p = &hb[(size_t)par*HDIM + j];
                u64 pk = __hip_atomic_load(p, __ATOMIC_RELAXED, __HIP_MEMORY_SCOPE_AGENT);
                while ((u32)(pk >> 32) != want){
                    pk = __hip_atomic_load(p, __ATOMIC_RELAXED, __HIP_MEMORY_SCOPE_AGENT);
                }
                h_sh[par][j] = __uint_as_float((u32)pk);
            }
        }
        __syncthreads();              // the ONLY barrier per step

        // ---- half-row dot: 32 x (b128 w, b128 h-broadcast) ----
        float acc = 0.0f;
        {
            const float* hbase = h_sh[par] + half*128;
            #pragma unroll
            for (int i = 0; i < 32; ++i){
                const int byte = (rb*1024 + half*512 + i*16) ^ ((rb&7)<<4);
                const float4 wv = *reinterpret_cast<const float4*>(wbuf + byte);
                const float4 hv = *reinterpret_cast<const float4*>(hbase + i*4);
                acc = fmaf(wv.x, hv.x, fmaf(wv.y, hv.y, fmaf(wv.z, hv.z, fmaf(wv.w, hv.w, acc))));
            }
        }
        // ---- combine halves (adjacent lanes), gates in-wave ----
        const float other = __shfl_xor(acc, 1, 64);
        const float sfull = (half == 0) ? (xgc + (acc + other)) : 0.0f;
        const float val = (g_r == 2) ? tanhf(sfull) : sigf(sfull);  // even lanes valid
        const int base = l & 56;                      // 8*uu
        const float f_ = __shfl(val, base + 2, 64);
        const float g_ = __shfl(val, base + 4, 64);
        const float o_ = __shfl(val, base + 6, 64);
        if (prod){
            c = f_*c + val*g_;                        // val = i-gate here
            const float h = o_*tanhf(c);
            const u64 pk = ((u64)(u32)(t+1) << 32) | (u64)__float_as_uint(h);
            __hip_atomic_store(&hb[(size_t)((t+1)&1)*HDIM + ug], pk,
                               __ATOMIC_RELAXED, __HIP_MEMORY_SCOPE_AGENT);
            h_sh[(t+1)&1][ug] = h;                    // own-block fast path
            hs[(size_t)(d==0 ? t : (T_LEN-1-t))*HDIM + ug] = h;
        }
        if (half == 0 && t+1 < T_LEN)
            xgc = xg[(size_t)(t+1)*G4 + row_global];  // prefetch next xg
    }
}

// ---------------------------------------------------------------------------
// K3: feats[t][tag] = [hf[t]; hb[t]] . W_out[tag] + b_out[tag]  (f32)
// ---------------------------------------------------------------------------
__global__ __launch_bounds__(256) void k_feats(
    const float* __restrict__ hs_f, const float* __restrict__ hs_b,
    const float* __restrict__ W_out, const float* __restrict__ b_out,
    float* __restrict__ feats)
{
    __shared__ __align__(16) float fsh[8][512];
    const int tb = blockIdx.x, j = threadIdx.x;
    #pragma unroll
    for (int r=0;r<8;++r){
        const int t = tb*8 + r;
        fsh[r][j]       = hs_f[(size_t)t*HDIM + j];
        fsh[r][256 + j] = hs_b[(size_t)t*HDIM + j];
    }
    __syncthreads();
    const int tsub = j >> 5, tag = j & 31;
    const float4* wr = reinterpret_cast<const float4*>(W_out + (size_t)tag*512);
    float acc = b_out[tag];
    for (int kk=0; kk<128; ++kk){
        float4 wvv = wr[kk];
        float4 hv = reinterpret_cast<const float4*>(fsh[tsub])[kk];
        acc = fmaf(wvv.x, hv.x, fmaf(wvv.y, hv.y, fmaf(wvv.z, hv.z, fmaf(wvv.w, hv.w, acc))));
    }
    feats[(size_t)(tb*8+tsub)*NTAGS + tag] = acc;
}

// ---------------------------------------------------------------------------
// K4: Viterbi in f32 (only the score binds: path flips cost <=31 << 183).
// Wave 0 scans; waves 1-3 double-buffer feat chunks. LDS-chunked backtrace.
// ---------------------------------------------------------------------------
__global__ __launch_bounds__(256,1) void k_viterbi(
    const float* __restrict__ feats, const float* __restrict__ trans,
    unsigned char* __restrict__ bp_g, float* __restrict__ out)
{
    __shared__ __align__(16) float fbuf[2][256*NTAGS];   // 2 x 32KB
    __shared__ float fv_sh[NTAGS];
    __shared__ float term_sh[NTAGS];
    __shared__ int best_sh;
    const int j = threadIdx.x;
    const int n = j & 31, ph = (j >> 5) & 1;
    const bool scanlane = (j < 64);
    float tr[16];
    if (scanlane){
        #pragma unroll
        for (int i=0;i<16;++i) tr[i] = trans[n*NTAGS + ph*16 + i];
    }
    float fv = (n == START_TAG) ? 0.0f : -10000.0f;

    const int CH = 256, NCH = T_LEN / CH;  // 16 chunks
    for (int idx = j; idx < CH*NTAGS; idx += 256) fbuf[0][idx] = feats[idx];
    __syncthreads();
    for (int cc = 0; cc < NCH; ++cc){
        const int buf = cc & 1;
        if (scanlane){
            for (int s = 0; s < CH; ++s){
                const int t = cc*CH + s;
                const float f = fbuf[buf][s*NTAGS + n];
                if (ph == 0) fv_sh[n] = fv;      // same-wave lockstep publish
                float bestv = -1e30f; int bestp = 0;
                #pragma unroll
                for (int i=0;i<16;++i){
                    const int p = ph*16 + i;
                    const float v = fv_sh[p] + tr[i];
                    if (v > bestv){ bestv = v; bestp = p; }   // strict > = first index
                }
                const float ov = __shfl_xor(bestv, 32, 64);
                const int   op = __shfl_xor(bestp, 32, 64);
                const float lowv  = ph ? ov    : bestv;
                const int   lowp  = ph ? op    : bestp;
                const float highv = ph ? bestv : ov;
                const int   highp = ph ? bestp : op;
                float wvv = lowv; int wp = lowp;
                if (highv > lowv){ wvv = highv; wp = highp; } // low half wins ties
                if (ph == 0) bp_g[(size_t)t*NTAGS + n] = (unsigned char)wp;
                fv = wvv + f;
            }
        } else if (cc + 1 < NCH){
            const int nb = (cc+1) & 1;
            const float* src = feats + (size_t)(cc+1)*CH*NTAGS;
            for (int idx = j - 64; idx < CH*NTAGS; idx += 192) fbuf[nb][idx] = src[idx];
        }
        __syncthreads();
    }

    if (scanlane && ph == 0) term_sh[n] = fv + trans[STOP_TAG*NTAGS + n];
    __syncthreads();
    if (j == 0){
        float bv = term_sh[0]; int bi = 0;
        for (int p = 1; p < NTAGS; ++p){
            if (term_sh[p] > bv){ bv = term_sh[p]; bi = p; }
        }
        out[0] = bv;
        out[1 + (T_LEN-1)] = (float)bi;
        best_sh = bi;
    }
    __syncthreads();
    // backtrace, 1024-step LDS chunks
    unsigned char* bp_sh = reinterpret_cast<unsigned char*>(fbuf);
    int b = best_sh;
    for (int cc2 = 3; cc2 >= 0; --cc2){
        const u32* src = reinterpret_cast<const u32*>(bp_g + (size_t)cc2*1024*NTAGS);
        u32* dst = reinterpret_cast<u32*>(bp_sh);
        for (int idx = j; idx < 8192; idx += 256) dst[idx] = src[idx];
        __syncthreads();
        if (j == 0){
            for (int tt = 1023; tt >= 0; --tt){
                const int t = cc2*1024 + tt;
                if (t == 0) break;                 // step into <START> dropped
                const int nb2 = bp_sh[tt*NTAGS + b];
                out[1 + (t-1)] = (float)nb2;
                b = nb2;
            }
        }
        __syncthreads();
    }
}

// ---------------------------------------------------------------------------
extern "C" void kernel_launch(void* const* d_in, const int* in_sizes, int n_in,
                              void* d_out, int out_size, void* d_ws, size_t ws_size,
                              hipStream_t stream)
{
    const int*   seq   = (const int*)  d_in[0];
    const float* E     = (const float*)d_in[1];
    const float* Wih_f = (const float*)d_in[2];
    const float* Whh_f = (const float*)d_in[3];
    const float* bih_f = (const float*)d_in[4];
    const float* bhh_f = (const float*)d_in[5];
    const float* Wih_b = (const float*)d_in[6];
    const float* Whh_b = (const float*)d_in[7];
    const float* bih_b = (const float*)d_in[8];
    const float* bhh_b = (const float*)d_in[9];
    const float* h0    = (const float*)d_in[10];
    const float* c0    = (const float*)d_in[11];
    const float* W_out = (const float*)d_in[12];
    const float* b_out = (const float*)d_in[13];
    const float* trans = (const float*)d_in[14];

    char* ws = (char*)d_ws;
    float* xg_f  = (float*)(ws);                                 // 16 MB
    float* xg_b  = (float*)(ws + (size_t)(16u<<20));             // 16 MB
    float* hs_f  = (float*)(ws + (size_t)(32u<<20));             // 4 MB
    float* hs_b  = (float*)(ws + (size_t)(36u<<20));             // 4 MB
    float* feats = (float*)(ws + (size_t)(40u<<20));             // 512 KB
    unsigned char* bp = (unsigned char*)(ws + (size_t)(40u<<20) + (512u<<10)); // 128 KB
    u64* hbuf    = (u64*)(ws + (size_t)(40u<<20) + (640u<<10));  // 8 KB

    k_xg<<<dim3(4096), dim3(256), 0, stream>>>(seq, E, Wih_f, bih_f, bhh_f,
                                               Wih_b, bih_b, bhh_b, xg_f, xg_b);
    k_lstm<<<dim3(16), dim3(256), 0, stream>>>(Whh_f, Whh_b, xg_f, xg_b, h0, c0, hs_f, hs_b, hbuf);
    k_feats<<<dim3(512), dim3(256), 0, stream>>>(hs_f, hs_b, W_out, b_out, feats);
    k_viterbi<<<dim3(1), dim3(256), 0, stream>>>(feats, trans, bp, (float*)d_out);
}

// Round 9
// 9292.110 us; speedup vs baseline: 1.0694x; 1.0694x over previous
//
#include <hip/hip_runtime.h>
#include <hip/hip_bf16.h>
#include <stdint.h>

#define T_LEN 4096
#define D_DIM 256
#define HDIM 256
#define G4 1024          // 4*HD gate rows per direction
#define NTAGS 32
#define START_TAG 30
#define STOP_TAG 31

typedef unsigned long long u64;
typedef unsigned int u32;

__device__ __forceinline__ float sigf(float x){ return 1.0f/(1.0f+expf(-x)); }

// ---------------------------------------------------------------------------
// K1: embedding gather + input projections xg = E[seq] @ Wih^T + (bih+bhh).
// r9 rewrite: 256 blocks (8 col-tiles x 32 t-chains of 128 t in 4 sub-tiles
// of 32). Weight rows re-read 16x total (was 512x = ~1GB): per-thread row
// stays L1/L2-hot across 128 t. x rows staged in LDS, read as broadcast.
// acc[32] fully unrolled (static indexing only).
// ---------------------------------------------------------------------------
__global__ __launch_bounds__(256) void k_xg(const int* __restrict__ seq,
    const float* __restrict__ E,
    const float* __restrict__ Wf, const float* __restrict__ bihf, const float* __restrict__ bhhf,
    const float* __restrict__ Wb, const float* __restrict__ bihb, const float* __restrict__ bhhb,
    float* __restrict__ xg_f, float* __restrict__ xg_b)
{
    __shared__ __align__(16) float xsh[32][D_DIM];   // 32 KB
    const int cb = blockIdx.x & 7;        // col-tile
    const int tg = blockIdx.x >> 3;       // t-chain [0,32)
    const int j  = threadIdx.x;
    const int col = cb*256 + j;           // 0..2047
    const int d   = col >> 10;            // 0 fwd, 1 bwd
    const int row = col & 1023;
    const float* W = d ? Wb : Wf;
    const float bias = d ? (bihb[row] + bhhb[row]) : (bihf[row] + bhhf[row]);
    const float4* wr = reinterpret_cast<const float4*>(W + (size_t)row*D_DIM);

    for (int s = 0; s < 4; ++s){
        const int t0 = tg*128 + s*32;
        __syncthreads();                  // previous sub-tile's xsh reads done
        for (int r2 = 0; r2 < 32; ++r2){
            const int sqv = seq[t0 + r2];             // uniform -> scalar load
            xsh[r2][j] = E[(size_t)sqv*D_DIM + j];    // coalesced row
        }
        __syncthreads();
        float acc[32];
        #pragma unroll
        for (int r2 = 0; r2 < 32; ++r2) acc[r2] = 0.f;
        for (int kk = 0; kk < D_DIM/4; ++kk){
            const float4 wv = wr[kk];
            #pragma unroll
            for (int r2 = 0; r2 < 32; ++r2){
                const float4 xv = reinterpret_cast<const float4*>(xsh[r2])[kk]; // broadcast
                acc[r2] = fmaf(wv.x, xv.x, fmaf(wv.y, xv.y, fmaf(wv.z, xv.z, fmaf(wv.w, xv.w, acc[r2]))));
            }
        }
        #pragma unroll
        for (int r2 = 0; r2 < 32; ++r2){
            const int t = t0 + r2;
            const float v = acc[r2] + bias;
            if (d == 0) xg_f[(size_t)t*G4 + row] = v;
            else        xg_b[(size_t)(T_LEN-1-t)*G4 + row] = v;
        }
    }
}

// ---------------------------------------------------------------------------
// K2: bidirectional LSTM. 64 persistent blocks (2 dir x 32), 8 units each —
// EXACT r6 exchange (packed tag|h agent atomics, tight poll, wave-private
// h slices, ONE barrier/step; r8's sc0-only L2 poll deadlocked: unverified
// cache scope inside an unbounded poll = hang; never again).
// r9 tail-shaving on the r6 skeleton:
//  * in-wave k-slice pair reduce via __shfl_xor(32): partial writes 8->4.
//  * gates DISTRIBUTED across all 4 waves (wave w owns units 2w,2w+1; its
//    lanes 0..7 compute the 8 gate-rows, 3 shuffles, lanes 0..1 do c/h +
//    publish). Parallelizes the old single-wave ~400cy gate tail.
//  * xg loads only by the 8 gate lanes/wave (was all 256 threads).
// Gate-sum order differs from r6 -> tiny f32 drift (sanctioned: path flips
// cost <=31, score tol 183).
// ---------------------------------------------------------------------------
__global__ __launch_bounds__(256,1) void k_lstm(
    const float* __restrict__ Whh_f, const float* __restrict__ Whh_b,
    const float* __restrict__ xgf, const float* __restrict__ xgb,
    const float* __restrict__ h0, const float* __restrict__ c0,
    float* __restrict__ hs_f, float* __restrict__ hs_b,
    u64* __restrict__ hbuf_all)
{
    const int blk = blockIdx.x;       // 0..63
    const int d   = blk >> 5;         // direction
    const int sb  = blk & 31;         // sub-block within direction
    const int ulo = sb * 8;           // first owned unit
    const int j = threadIdx.x;        // 0..255
    const int r = j & 31;             // row_local in [0,32)
    const int o = j >> 5;             // k-slice (32 k each)
    const int w = j >> 6;             // wave id
    const int l = j & 63;             // lane
    const int g_r = r >> 3;           // gate of this row
    const int u_r = r & 7;            // unit offset
    const int row_global = g_r*256 + ulo + u_r;   // in [0,1024)

    const float* __restrict__ Whh = d ? Whh_b : Whh_f;
    const float* __restrict__ xg  = d ? xgb : xgf;
    float* __restrict__ hs = d ? hs_b : hs_f;
    u64* __restrict__ hb = hbuf_all + (size_t)d*2*HDIM;   // [parity][unit]

    __shared__ __align__(16) char wbuf[32*1024];  // [r][k] f32, swizzled (r6)
    __shared__ float h_sh[HDIM];                  // wave w owns [64w,64w+64)
    __shared__ float partial[2*128];              // [parity][w][r]

    // ---- stage weights (r6 layout) ----
    {
        const float4* src = reinterpret_cast<const float4*>(Whh + (size_t)row_global*HDIM + o*32);
        #pragma unroll
        for (int i = 0; i < 8; ++i){
            *reinterpret_cast<float4*>(wbuf + ((r*1024 + (o*8+i)*16) ^ ((r&7)<<4))) = src[i];
        }
    }
    h_sh[j] = h0[d*HDIM + j];

    // gate-lane setup: wave w, lanes l<8 handle rows (g2 = l>>1, u2 = 2w+(l&1))
    const int g2 = l >> 1;
    const int u2 = 2*w + (l & 1);
    const int gate_row_global = g2*256 + ulo + u2;     // valid for l<8
    float c   = (l < 2) ? c0[d*HDIM + ulo + u2] : 0.0f;
    float xgc = (l < 8) ? xg[gate_row_global] : 0.0f;  // xg[0][gate row]
    __syncthreads();

    for (int t = 0; t < T_LEN; ++t){
        const int par = t & 1;
        if (t > 0){
            // poll unit j (tag t): wave-private h slice, no barrier needed
            const u32 want = (u32)t;
            u64* p = &hb[(size_t)par*HDIM + j];
            u64 pk = __hip_atomic_load(p, __ATOMIC_RELAXED, __HIP_MEMORY_SCOPE_AGENT);
            while ((u32)(pk >> 32) != want)
                pk = __hip_atomic_load(p, __ATOMIC_RELAXED, __HIP_MEMORY_SCOPE_AGENT);
            h_sh[j] = __uint_as_float((u32)pk);
            asm volatile("s_waitcnt lgkmcnt(0)" ::: "memory");   // wave-level fence
        }
        // ---- dot: row r, k in [o*32, o*32+32) ----
        float acc = 0.0f;
        {
            const float4* hvp = reinterpret_cast<const float4*>(h_sh + o*32);
            #pragma unroll
            for (int i = 0; i < 8; ++i){
                float4 wv = *reinterpret_cast<const float4*>(wbuf + ((r*1024 + (o*8+i)*16) ^ ((r&7)<<4)));
                float4 hv = hvp[i];
                acc = fmaf(wv.x, hv.x, fmaf(wv.y, hv.y, fmaf(wv.z, hv.z, fmaf(wv.w, hv.w, acc))));
            }
        }
        acc += __shfl_xor(acc, 32, 64);               // pair k-slices in-wave
        if ((j & 32) == 0) partial[par*128 + w*32 + r] = acc;
        __syncthreads();              // the ONLY barrier per step
        if (l < 8){                   // per-wave gates: 8 rows of units 2w,2w+1
            const int rr = g2*8 + u2;
            const float* pp = partial + par*128;
            const float s = xgc + ((pp[rr] + pp[32+rr]) + (pp[64+rr] + pp[96+rr]));
            const float val = (g2 == 2) ? tanhf(s) : sigf(s);
            const float f_ = __shfl(val, 2 + (l&1), 64);
            const float g_ = __shfl(val, 4 + (l&1), 64);
            const float o_ = __shfl(val, 6 + (l&1), 64);
            if (l < 2){
                c = f_*c + val*g_;                    // val = i-gate here
                const float h = o_*tanhf(c);
                const int ug = ulo + u2;
                const u64 pk = ((u64)(u32)(t+1) << 32) | (u64)__float_as_uint(h);
                __hip_atomic_store(&hb[(size_t)((t+1)&1)*HDIM + ug], pk,
                                   __ATOMIC_RELAXED, __HIP_MEMORY_SCOPE_AGENT);
                hs[(size_t)(d==0 ? t : (T_LEN-1-t))*HDIM + ug] = h;
            }
            if (t+1 < T_LEN)
                xgc = xg[(size_t)(t+1)*G4 + gate_row_global];   // prefetch
        }
    }
}

// ---------------------------------------------------------------------------
// K3: feats[t][tag] = [hf[t]; hb[t]] . W_out[tag] + b_out[tag]  (f32)
// ---------------------------------------------------------------------------
__global__ __launch_bounds__(256) void k_feats(
    const float* __restrict__ hs_f, const float* __restrict__ hs_b,
    const float* __restrict__ W_out, const float* __restrict__ b_out,
    float* __restrict__ feats)
{
    __shared__ __align__(16) float fsh[8][512];
    const int tb = blockIdx.x, j = threadIdx.x;
    #pragma unroll
    for (int r=0;r<8;++r){
        const int t = tb*8 + r;
        fsh[r][j]       = hs_f[(size_t)t*HDIM + j];
        fsh[r][256 + j] = hs_b[(size_t)t*HDIM + j];
    }
    __syncthreads();
    const int tsub = j >> 5, tag = j & 31;
    const float4* wr = reinterpret_cast<const float4*>(W_out + (size_t)tag*512);
    float acc = b_out[tag];
    for (int kk=0; kk<128; ++kk){
        float4 wvv = wr[kk];
        float4 hv = reinterpret_cast<const float4*>(fsh[tsub])[kk];
        acc = fmaf(wvv.x, hv.x, fmaf(wvv.y, hv.y, fmaf(wvv.z, hv.z, fmaf(wvv.w, hv.w, acc))));
    }
    feats[(size_t)(tb*8+tsub)*NTAGS + tag] = acc;
}

// ---------------------------------------------------------------------------
// K4: Viterbi in f32 (only the score binds: path flips cost <=31 << 183).
// Wave 0 scans; waves 1-3 double-buffer feat chunks. LDS-chunked backtrace.
// ---------------------------------------------------------------------------
__global__ __launch_bounds__(256,1) void k_viterbi(
    const float* __restrict__ feats, const float* __restrict__ trans,
    unsigned char* __restrict__ bp_g, float* __restrict__ out)
{
    __shared__ __align__(16) float fbuf[2][256*NTAGS];   // 2 x 32KB
    __shared__ float fv_sh[NTAGS];
    __shared__ float term_sh[NTAGS];
    __shared__ int best_sh;
    const int j = threadIdx.x;
    const int n = j & 31, ph = (j >> 5) & 1;
    const bool scanlane = (j < 64);
    float tr[16];
    if (scanlane){
        #pragma unroll
        for (int i=0;i<16;++i) tr[i] = trans[n*NTAGS + ph*16 + i];
    }
    float fv = (n == START_TAG) ? 0.0f : -10000.0f;

    const int CH = 256, NCH = T_LEN / CH;  // 16 chunks
    for (int idx = j; idx < CH*NTAGS; idx += 256) fbuf[0][idx] = feats[idx];
    __syncthreads();
    for (int cc = 0; cc < NCH; ++cc){
        const int buf = cc & 1;
        if (scanlane){
            for (int s = 0; s < CH; ++s){
                const int t = cc*CH + s;
                const float f = fbuf[buf][s*NTAGS + n];
                if (ph == 0) fv_sh[n] = fv;      // same-wave lockstep publish
                float bestv = -1e30f; int bestp = 0;
                #pragma unroll
                for (int i=0;i<16;++i){
                    const int p = ph*16 + i;
                    const float v = fv_sh[p] + tr[i];
                    if (v > bestv){ bestv = v; bestp = p; }   // strict > = first index
                }
                const float ov = __shfl_xor(bestv, 32, 64);
                const int   op = __shfl_xor(bestp, 32, 64);
                const float lowv  = ph ? ov    : bestv;
                const int   lowp  = ph ? op    : bestp;
                const float highv = ph ? bestv : ov;
                const int   highp = ph ? bestp : op;
                float wvv = lowv; int wp = lowp;
                if (highv > lowv){ wvv = highv; wp = highp; } // low half wins ties
                if (ph == 0) bp_g[(size_t)t*NTAGS + n] = (unsigned char)wp;
                fv = wvv + f;
            }
        } else if (cc + 1 < NCH){
            const int nb = (cc+1) & 1;
            const float* src = feats + (size_t)(cc+1)*CH*NTAGS;
            for (int idx = j - 64; idx < CH*NTAGS; idx += 192) fbuf[nb][idx] = src[idx];
        }
        __syncthreads();
    }

    if (scanlane && ph == 0) term_sh[n] = fv + trans[STOP_TAG*NTAGS + n];
    __syncthreads();
    if (j == 0){
        float bv = term_sh[0]; int bi = 0;
        for (int p = 1; p < NTAGS; ++p){
            if (term_sh[p] > bv){ bv = term_sh[p]; bi = p; }
        }
        out[0] = bv;
        out[1 + (T_LEN-1)] = (float)bi;
        best_sh = bi;
    }
    __syncthreads();
    // backtrace, 1024-step LDS chunks
    unsigned char* bp_sh = reinterpret_cast<unsigned char*>(fbuf);
    int b = best_sh;
    for (int cc2 = 3; cc2 >= 0; --cc2){
        const u32* src = reinterpret_cast<const u32*>(bp_g + (size_t)cc2*1024*NTAGS);
        u32* dst = reinterpret_cast<u32*>(bp_sh);
        for (int idx = j; idx < 8192; idx += 256) dst[idx] = src[idx];
        __syncthreads();
        if (j == 0){
            for (int tt = 1023; tt >= 0; --tt){
                const int t = cc2*1024 + tt;
                if (t == 0) break;                 // step into <START> dropped
                const int nb2 = bp_sh[tt*NTAGS + b];
                out[1 + (t-1)] = (float)nb2;
                b = nb2;
            }
        }
        __syncthreads();
    }
}

// ---------------------------------------------------------------------------
extern "C" void kernel_launch(void* const* d_in, const int* in_sizes, int n_in,
                              void* d_out, int out_size, void* d_ws, size_t ws_size,
                              hipStream_t stream)
{
    const int*   seq   = (const int*)  d_in[0];
    const float* E     = (const float*)d_in[1];
    const float* Wih_f = (const float*)d_in[2];
    const float* Whh_f = (const float*)d_in[3];
    const float* bih_f = (const float*)d_in[4];
    const float* bhh_f = (const float*)d_in[5];
    const float* Wih_b = (const float*)d_in[6];
    const float* Whh_b = (const float*)d_in[7];
    const float* bih_b = (const float*)d_in[8];
    const float* bhh_b = (const float*)d_in[9];
    const float* h0    = (const float*)d_in[10];
    const float* c0    = (const float*)d_in[11];
    const float* W_out = (const float*)d_in[12];
    const float* b_out = (const float*)d_in[13];
    const float* trans = (const float*)d_in[14];

    char* ws = (char*)d_ws;
    float* xg_f  = (float*)(ws);                                 // 16 MB
    float* xg_b  = (float*)(ws + (size_t)(16u<<20));             // 16 MB
    float* hs_f  = (float*)(ws + (size_t)(32u<<20));             // 4 MB
    float* hs_b  = (float*)(ws + (size_t)(36u<<20));             // 4 MB
    float* feats = (float*)(ws + (size_t)(40u<<20));             // 512 KB
    unsigned char* bp = (unsigned char*)(ws + (size_t)(40u<<20) + (512u<<10)); // 128 KB
    u64* hbuf    = (u64*)(ws + (size_t)(40u<<20) + (640u<<10));  // 8 KB

    k_xg<<<dim3(256), dim3(256), 0, stream>>>(seq, E, Wih_f, bih_f, bhh_f,
                                              Wih_b, bih_b, bhh_b, xg_f, xg_b);
    k_lstm<<<dim3(64), dim3(256), 0, stream>>>(Whh_f, Whh_b, xg_f, xg_b, h0, c0, hs_f, hs_b, hbuf);
    k_feats<<<dim3(512), dim3(256), 0, stream>>>(hs_f, hs_b, W_out, b_out, feats);
    k_viterbi<<<dim3(1), dim3(256), 0, stream>>>(feats, trans, bp, (float*)d_out);
}